// Round 13
// baseline (539.641 us; speedup 1.0000x reference)
//
#include <hip/hip_runtime.h>
#include <hip/hip_bf16.h>

#define EPS 1e-5f

typedef _Float16 half_t;
typedef __attribute__((ext_vector_type(8))) _Float16 h16x8;
typedef __attribute__((ext_vector_type(4))) _Float16 h16x4;
typedef __attribute__((ext_vector_type(4))) float f32x4;

__device__ __forceinline__ float relu_f(float x) { return x > 0.f ? x : 0.f; }

// ---------------- workspace layout (float units) ----------------
#define OFF_Y1   0
#define OFF_Y2   17743872
#define OFF_Y3   22179840
#define OFF_Y4   23408640
#define OFF_ST   23715840
#define OFF_WHL  23718912
// aliases inside y1 region (y1 dead after conv2):
#define OFF_A    0
#define OFF_BV   3276800
#define OFF_XG   6553600
// free hole: y1 as f16 uses only floats [0, 8871936) of its legacy region:
#define OFF_WHL2 8871936

// ---------------- prep: zero stats + cast g_w2..4 to f16, swizzled to A-frag lane order ----
__global__ __launch_bounds__(256) void k_prep(const float* w2, const float* w3,
                                              const float* w4, half_t* whl, float* stats) {
    int idx = blockIdx.x * 256 + threadIdx.x;     // grid exact: 768*256 = 3*65536
    if (idx < 3072) stats[idx] = 0.f;
    int l = idx >> 16, e = idx & 65535;
    const float* w = (l == 0) ? w2 : (l == 1) ? w3 : w4;
    float v = w[e];
    int c = e >> 8, k = e & 255;
    int o = ((c >> 4) * 8 + (k >> 5)) * 512 + ((k >> 3) & 3) * 128 + (c & 15) * 8 + (k & 7);
    whl[l * 65536 + o] = (half_t)v;
}

// ---------------- prep2: conv2 weights -> B-frag layout (K=tap*24+ic pad 224, oc pad 32) ---
__global__ __launch_bounds__(256) void k_prep2(const float* w2, half_t* whl2) {
    int idx = blockIdx.x * 256 + threadIdx.x;     // 28*256 = 7168 exact
    int ntile = idx / 3584, r = idx % 3584;
    int ks = r / 512, w = r % 512;
    int quad = w / 128, l15 = (w >> 3) & 15, j = w & 7;
    int k = ks * 32 + quad * 8 + j;
    int oc = ntile * 16 + l15;
    float v = 0.f;
    if (k < 216 && oc < 24) {
        int tap = k / 24, ic = k % 24;
        v = w2[(oc * 24 + ic) * 9 + tap];
    }
    whl2[idx] = (half_t)v;
}

// ---------------- conv1: 3->24 ch, 75->38, stride2 pad1, 2 images/thread ------------------
__global__ __launch_bounds__(256, 2) void k_conv1(const float* img, const float* w,
                                                  const float* bias, half_t* y1, float* ostats) {
    __shared__ float wl[648], bl[24], red[4][48];
    int tid = threadIdx.x;
    if (tid < 24) bl[tid] = bias[tid];
    for (int i = tid; i < 648; i += 256) wl[i] = w[i];
    __syncthreads();
    int idx = blockIdx.x * 256 + tid;      // 1444*256 = 256*1444 exact (image-pairs)
    int b2 = idx / 1444, rem = idx % 1444;
    int b0 = b2 * 2;
    int oh = rem / 38, ow = rem % 38;
    float acc0[24], acc1[24];
#pragma unroll
    for (int o = 0; o < 24; ++o) { acc0[o] = bl[o]; acc1[o] = bl[o]; }
    for (int ic = 0; ic < 3; ++ic) {
        float p0[9], p1[9];
#pragma unroll
        for (int kh = 0; kh < 3; ++kh) {
            int ih = oh * 2 - 1 + kh;
#pragma unroll
            for (int kw = 0; kw < 3; ++kw) {
                int iw = ow * 2 - 1 + kw;
                bool ok = (unsigned)ih < 75u && (unsigned)iw < 75u;
                p0[kh * 3 + kw] = ok ? img[((b0 * 3 + ic) * 75 + ih) * 75 + iw] : 0.f;
                p1[kh * 3 + kw] = ok ? img[(((b0 + 1) * 3 + ic) * 75 + ih) * 75 + iw] : 0.f;
            }
        }
#pragma unroll
        for (int o = 0; o < 24; ++o)
#pragma unroll
            for (int t = 0; t < 9; ++t) {
                float wv = wl[(o * 3 + ic) * 9 + t];
                acc0[o] += wv * p0[t];
                acc1[o] += wv * p1[t];
            }
    }
#pragma unroll
    for (int o = 0; o < 24; ++o) { acc0[o] = relu_f(acc0[o]); acc1[o] = relu_f(acc1[o]); }
#pragma unroll
    for (int g = 0; g < 3; ++g) {
        h16x8 a, c;
#pragma unroll
        for (int j = 0; j < 8; ++j) { a[j] = (half_t)acc0[g * 8 + j]; c[j] = (half_t)acc1[g * 8 + j]; }
        *(h16x8*)&y1[((long)(b0) * 1444 + rem) * 24 + g * 8] = a;
        *(h16x8*)&y1[((long)(b0 + 1) * 1444 + rem) * 24 + g * 8] = c;
    }
    int wave = tid >> 6;
#pragma unroll
    for (int o = 0; o < 24; ++o) {
        float v = acc0[o] + acc1[o];
        float v2 = acc0[o] * acc0[o] + acc1[o] * acc1[o];
#pragma unroll
        for (int off = 1; off < 64; off <<= 1) { v += __shfl_xor(v, off); v2 += __shfl_xor(v2, off); }
        if ((tid & 63) == 0) { red[wave][o] = v; red[wave][24 + o] = v2; }
    }
    __syncthreads();
    if (tid < 48)
        atomicAdd(&ostats[(blockIdx.x & 15) * 48 + tid],
                  red[0][tid] + red[1][tid] + red[2][tid] + red[3][tid]);
}

// ---------------- conv2 v5: MFMA im2col, 512 threads (R12: kept, -3.5us matched) -----------
__global__ __launch_bounds__(512) void k_conv2(const half_t* yin, const half_t* whl2,
                                               const float* bias, const float* instats,
                                               const float* bng, const float* bnb,
                                               float* yout, float* ostats) {
    __shared__ half_t yL[34672];          // 38*38*24 + zero slot @34656
    __shared__ half_t wf[7168];
    __shared__ float outL[8856];          // 24 x stride 369
    __shared__ float scs[24], shs[24], bl[24], red[8][48];
    int tid = threadIdx.x;
    int b = blockIdx.x;
    if (tid < 24) {
        float s = 0.f, s2 = 0.f;
#pragma unroll
        for (int k = 0; k < 16; ++k) { s += instats[k * 48 + tid]; s2 += instats[k * 48 + 24 + tid]; }
        float mu = s * (1.f / 739328.f);
        float var = s2 * (1.f / 739328.f) - mu * mu;
        float sca = bng[tid] * rsqrtf(var + EPS);
        scs[tid] = sca; shs[tid] = bnb[tid] - mu * sca;
        bl[tid] = bias[tid];
    }
    if (tid < 16) yL[34656 + tid] = (half_t)0.f;   // zero slot (+pad)
    for (int i = tid; i < 896; i += 512)
        ((h16x8*)wf)[i] = ((const h16x8*)whl2)[i];
    __syncthreads();
    // stage image with input-BN applied (channels per 8-chunk never wrap: 24 = 3*8)
    const half_t* ybase = yin + (long)b * 34656;
    for (int i = tid; i < 4332; i += 512) {
        h16x8 v = *(const h16x8*)&ybase[i * 8];
        int ch0 = (i % 3) * 8;
        h16x8 o;
#pragma unroll
        for (int j = 0; j < 8; ++j)
            o[j] = (half_t)((float)v[j] * scs[ch0 + j] + shs[ch0 + j]);
        *(h16x8*)&yL[i * 8] = o;
    }
    __syncthreads();
    int wv = tid >> 6, lane = tid & 63, quad = lane >> 4, l15 = lane & 15;
    float bb0 = bl[l15];
    float bb1 = (l15 < 8) ? bl[16 + l15] : 0.f;
    float s0 = 0.f, q0 = 0.f, s1 = 0.f, q1 = 0.f;
    int t0 = wv * 3, t1 = t0 + 3; if (t1 > 23) t1 = 23;
#pragma unroll 1
    for (int t = t0; t < t1; ++t) {
        int px0 = t * 16;
        int pxa = px0 + l15; if (pxa > 360) pxa = 360;   // A-row clamp; dead rows masked at D
        int oh = pxa / 19, ow = pxa % 19;
        f32x4 a0 = (f32x4){0.f, 0.f, 0.f, 0.f};
        f32x4 a1 = (f32x4){0.f, 0.f, 0.f, 0.f};
#pragma unroll
        for (int ks = 0; ks < 7; ++ks) {
            int k0 = ks * 32 + quad * 8;
            int tap = k0 / 24, ic0 = k0 - tap * 24;
            int kh = tap / 3, kw = tap - kh * 3;
            int ih = oh * 2 - 1 + kh, iw = ow * 2 - 1 + kw;
            bool val = (tap < 9) && ((unsigned)ih < 38u) && ((unsigned)iw < 38u);
            int aoff = val ? ((ih * 38 + iw) * 24 + ic0) : 34656;
            h16x8 af = *(const h16x8*)&yL[aoff];
            h16x8 w0 = *(const h16x8*)&wf[ks * 512 + quad * 128 + l15 * 8];
            h16x8 w1 = *(const h16x8*)&wf[3584 + ks * 512 + quad * 128 + l15 * 8];
            a0 = __builtin_amdgcn_mfma_f32_16x16x32_f16(af, w0, a0, 0, 0, 0);
            a1 = __builtin_amdgcn_mfma_f32_16x16x32_f16(af, w1, a1, 0, 0, 0);
        }
#pragma unroll
        for (int v = 0; v < 4; ++v) {
            int p = px0 + quad * 4 + v;                  // <= 367 < 369: unconditional LDS ok
            bool pv = p < 361;
            float x0 = relu_f(a0[v] + bb0);
            float x1 = relu_f(a1[v] + bb1);
            outL[l15 * 369 + p] = x0;
            if (l15 < 8) outL[(16 + l15) * 369 + p] = x1;
            if (pv) {
                s0 += x0; q0 += x0 * x0;
                if (l15 < 8) { s1 += x1; q1 += x1 * x1; }
            }
        }
    }
    // stats: reduce over quads (lanes sharing l15)
    s0 += __shfl_xor(s0, 16); s0 += __shfl_xor(s0, 32);
    q0 += __shfl_xor(q0, 16); q0 += __shfl_xor(q0, 32);
    s1 += __shfl_xor(s1, 16); s1 += __shfl_xor(s1, 32);
    q1 += __shfl_xor(q1, 16); q1 += __shfl_xor(q1, 32);
    if (quad == 0) {
        red[wv][l15] = s0; red[wv][24 + l15] = q0;
        if (l15 < 8) { red[wv][16 + l15] = s1; red[wv][40 + l15] = q1; }
    }
    __syncthreads();
    float* yo = yout + (long)b * 8664;
    for (int i = tid; i < 8664; i += 512) {
        int oc = i / 361, p = i - oc * 361;
        yo[i] = outL[oc * 369 + p];                      // y2 linear == (b*24+oc)*361+p
    }
    if (tid < 48) {
        float s = 0.f;
#pragma unroll
        for (int w2 = 0; w2 < 8; ++w2) s += red[w2][tid];
        atomicAdd(&ostats[(blockIdx.x & 15) * 48 + tid], s);
    }
}

// ---------------- conv3/4: 24->24, stride2 pad1; in-BN folded; fused out-stats ------------
__global__ __launch_bounds__(256) void k_conv(const float* yin, const float* w,
                                              const float* bias, const float* instats,
                                              const float* bng, const float* bnb,
                                              float* yout, float* ostats,
                                              int Hin, int Hout, float invN) {
    __shared__ float wl[5184], bl[24], sc[24], sh[24], red[4][48];
    int tid = threadIdx.x;
    if (tid < 24) {
        float s = 0.f, s2 = 0.f;
#pragma unroll
        for (int k = 0; k < 16; ++k) { s += instats[k * 48 + tid]; s2 += instats[k * 48 + 24 + tid]; }
        float mu = s * invN;
        float var = s2 * invN - mu * mu;
        float sca = bng[tid] * rsqrtf(var + EPS);
        sc[tid] = sca; sh[tid] = bnb[tid] - mu * sca;
        bl[tid] = bias[tid];
    }
    for (int i = tid; i < 5184; i += 256) wl[i] = w[i];
    __syncthreads();
    int idx = blockIdx.x * 256 + tid;      // grids exact
    int HWo = Hout * Hout;
    int b = idx / HWo, rem = idx % HWo;
    int oh = rem / Hout, ow = rem % Hout;
    float acc[24];
#pragma unroll
    for (int o = 0; o < 24; ++o) acc[o] = bl[o];
    for (int ic = 0; ic < 24; ++ic) {
        float patch[9];
        float scc = sc[ic], shc = sh[ic];
#pragma unroll
        for (int kh = 0; kh < 3; ++kh) {
            int ih = oh * 2 - 1 + kh;
#pragma unroll
            for (int kw = 0; kw < 3; ++kw) {
                int iw = ow * 2 - 1 + kw;
                bool ok = (unsigned)ih < (unsigned)Hin && (unsigned)iw < (unsigned)Hin;
                patch[kh * 3 + kw] = ok ? yin[((b * 24 + ic) * Hin + ih) * Hin + iw] * scc + shc : 0.f;
            }
        }
#pragma unroll
        for (int o = 0; o < 24; ++o)
#pragma unroll
            for (int t = 0; t < 9; ++t) acc[o] += wl[(o * 24 + ic) * 9 + t] * patch[t];
    }
    int wave = tid >> 6;
#pragma unroll
    for (int o = 0; o < 24; ++o) {
        acc[o] = relu_f(acc[o]);
        yout[(b * 24 + o) * HWo + rem] = acc[o];
        float v = acc[o], v2 = v * v;
#pragma unroll
        for (int off = 1; off < 64; off <<= 1) { v += __shfl_xor(v, off); v2 += __shfl_xor(v2, off); }
        if ((tid & 63) == 0) { red[wave][o] = v; red[wave][24 + o] = v2; }
    }
    __syncthreads();
    if (tid < 48)
        atomicAdd(&ostats[(blockIdx.x & 15) * 48 + tid],
                  red[0][tid] + red[1][tid] + red[2][tid] + red[3][tid]);
}

// ---------------- objects: bn4 + coords once into LDS, project through split g_w1 ----------
__global__ __launch_bounds__(256) void k_obj(const float* y4, const float* qst,
                                             const float* w1, const float* b1,
                                             const float* instats, const float* bng,
                                             const float* bnb, float* A, float* Bv, float* xg) {
    int b = blockIdx.x, tid = threadIdx.x;
    __shared__ float w1l[16128];
    __shared__ float objs[25][28];
    __shared__ float sc[24], sh[24], q[11];
    xg[b * 256 + tid] = 0.f;
    for (int i = tid; i < 16128; i += 256) w1l[i] = w1[i];
    if (tid < 24) {
        float s = 0.f, s2 = 0.f;
#pragma unroll
    for (int k = 0; k < 16; ++k) { s += instats[k * 48 + tid]; s2 += instats[k * 48 + 24 + tid]; }
        float mu = s * (1.f / 12800.f);
        float var = s2 * (1.f / 12800.f) - mu * mu;
        float sca = bng[tid] * rsqrtf(var + EPS);
        sc[tid] = sca; sh[tid] = bnb[tid] - mu * sca;
    }
    if (tid < 11) q[tid] = qst[b * 11 + tid];
    __syncthreads();
    for (int i = tid; i < 600; i += 256) {
        int c = i / 25, p = i % 25;
        objs[p][c] = y4[b * 600 + i] * sc[c] + sh[c];
    }
    if (tid < 25) { objs[tid][24] = ((tid / 5) - 2) * 0.5f; objs[tid][25] = ((tid % 5) - 2) * 0.5f; }
    __syncthreads();
    float wr[63];
#pragma unroll
    for (int k = 0; k < 63; ++k) wr[k] = w1l[tid * 63 + k];
    float qdot = b1[tid];
#pragma unroll
    for (int j = 0; j < 11; ++j) qdot += wr[52 + j] * q[j];
#pragma unroll 1
    for (int p = 0; p < 25; ++p) {
        float a = 0.f, bv = qdot;
#pragma unroll
        for (int k = 0; k < 26; ++k) { a += wr[k] * objs[p][k]; bv += wr[26 + k] * objs[p][k]; }
        A[(b * 25 + p) * 256 + tid] = a;
        Bv[(b * 25 + p) * 256 + tid] = bv;
    }
}

// ---------------- fused g-MLP v6: double-buffered h, ONE barrier per layer -----------------
// R12 audit: all 6 falsified k_g variants shared 2 barriers/layer (post-MFMA guard +
// post-write publish) = 6 rendezvous/block; diagnosed floor mechanism is barrier-lockstep
// pipe serialization (MFMA 40% + VALU 46% ~ sum 86%). v6: writes go to the OTHER h buffer,
// killing the guard barrier: stage|bar -> L0(rd h0, wr h1)|bar -> L1(rd h1, wr h0)|bar ->
// L2(rd h0, epilogue). 3 barriers. LDS 2x33.8+3 = 70.7KB -> 2 blocks/CU (pad-264 kept:
// stride-528B reads = free 2-way; dropping pad = 16-way conflict). Direct A/B of
// barrier-drain vs TLP: success = 135-142us; fail >= 158 -> revert to R12 k_g.
__global__ __launch_bounds__(256) void k_g(const float* A, const float* Bv, const half_t* whl,
                                           const float* gb2, const float* gb3,
                                           const float* gb4, float* xg) {
    __shared__ alignas(16) half_t h[2][64 * 264];
    __shared__ float biasL[3][256];
    int tid = threadIdx.x;
    int lb = (blockIdx.x & 7) * 640 + (blockIdx.x >> 3);   // XCD-contiguous (5120%8==0)
    int b = lb / 10, t = lb % 10;
    int r0 = t * 64;
    int rmax = 625 - r0; if (rmax > 64) rmax = 64;
    biasL[0][tid] = gb2[tid];
    biasL[1][tid] = gb3[tid];
    biasL[2][tid] = gb4[tid];
    const float* Ab = A + b * 6400;
    const float* Bb = Bv + b * 6400;
#pragma unroll
    for (int it = 0; it < 16; ++it) {
        int r = it * 4 + (tid >> 6);                       // wave-uniform row
        int rs = __builtin_amdgcn_readfirstlane(r);
        int pr = r0 + rs; if (pr > 624) pr = 624;          // clamp; masked at final sum
        int i = pr % 25, j = pr / 25;                      // scalar div/mod
        int c4 = (tid & 63) << 2;
        float4 av = *(const float4*)&Ab[i * 256 + c4];
        float4 bv = *(const float4*)&Bb[j * 256 + c4];
        h16x4 hv = {(half_t)relu_f(av.x + bv.x), (half_t)relu_f(av.y + bv.y),
                    (half_t)relu_f(av.z + bv.z), (half_t)relu_f(av.w + bv.w)};
        *(h16x4*)&h[0][r * 264 + c4] = hv;
    }
    __syncthreads();
    int cg = tid >> 6, lane = tid & 63;                    // 4 waves = 4 channel-groups
    int quad = lane >> 4, l15 = lane & 15;
    const half_t* Wl = whl + (cg * 4) * 8 * 512 + lane * 8;  // wave's W base (mi=0, ks=0)
#pragma unroll 1
    for (int layer = 0; layer < 3; ++layer) {
        int rb = layer & 1;                                // L0:h0, L1:h1, L2:h0
        const half_t* hr = &h[rb][l15 * 264];              // this lane's row base
        half_t* hw = &h[rb ^ 1][0];                        // write side (other buffer)
        const half_t* W = Wl + layer * 65536;
        f32x4 acc[4][4];
#pragma unroll
        for (int mi = 0; mi < 4; ++mi)
#pragma unroll
            for (int nt = 0; nt < 4; ++nt) acc[mi][nt] = (f32x4){0.f, 0.f, 0.f, 0.f};
        // prologue: ks=0 operands in flight
        h16x8 aw0 = *(const h16x8*)&W[0 * 4096];
        h16x8 aw1 = *(const h16x8*)&W[1 * 4096];
        h16x8 aw2 = *(const h16x8*)&W[2 * 4096];
        h16x8 aw3 = *(const h16x8*)&W[3 * 4096];
        h16x8 bh0 = *(const h16x8*)&hr[0 * 4224 + quad * 8];
        h16x8 bh1 = *(const h16x8*)&hr[1 * 4224 + quad * 8];
#pragma unroll 2
        for (int ks = 0; ks < 8; ++ks) {
            int ko = ks * 32 + quad * 8;
            int ksn = (ks + 1) & 7;                 // wrap: harmless redundant load at ks=7
            int kon = ksn * 32 + quad * 8;
            // this-iter second half (covered by nt=0,1 MFMA burst):
            h16x8 bh2 = *(const h16x8*)&hr[2 * 4224 + ko];
            h16x8 bh3 = *(const h16x8*)&hr[3 * 4224 + ko];
            // next-iter W (covered by full 16-MFMA burst):
            h16x8 an0 = *(const h16x8*)&W[0 * 4096 + ksn * 512];
            h16x8 an1 = *(const h16x8*)&W[1 * 4096 + ksn * 512];
            h16x8 an2 = *(const h16x8*)&W[2 * 4096 + ksn * 512];
            h16x8 an3 = *(const h16x8*)&W[3 * 4096 + ksn * 512];
            __builtin_amdgcn_s_setprio(1);
            acc[0][0] = __builtin_amdgcn_mfma_f32_16x16x32_f16(aw0, bh0, acc[0][0], 0, 0, 0);
            acc[1][0] = __builtin_amdgcn_mfma_f32_16x16x32_f16(aw1, bh0, acc[1][0], 0, 0, 0);
            acc[2][0] = __builtin_amdgcn_mfma_f32_16x16x32_f16(aw2, bh0, acc[2][0], 0, 0, 0);
            acc[3][0] = __builtin_amdgcn_mfma_f32_16x16x32_f16(aw3, bh0, acc[3][0], 0, 0, 0);
            acc[0][1] = __builtin_amdgcn_mfma_f32_16x16x32_f16(aw0, bh1, acc[0][1], 0, 0, 0);
            acc[1][1] = __builtin_amdgcn_mfma_f32_16x16x32_f16(aw1, bh1, acc[1][1], 0, 0, 0);
            acc[2][1] = __builtin_amdgcn_mfma_f32_16x16x32_f16(aw2, bh1, acc[2][1], 0, 0, 0);
            acc[3][1] = __builtin_amdgcn_mfma_f32_16x16x32_f16(aw3, bh1, acc[3][1], 0, 0, 0);
            // next-iter first half (covered by nt=2,3 MFMA burst):
            h16x8 bn0 = *(const h16x8*)&hr[0 * 4224 + kon];
            h16x8 bn1 = *(const h16x8*)&hr[1 * 4224 + kon];
            acc[0][2] = __builtin_amdgcn_mfma_f32_16x16x32_f16(aw0, bh2, acc[0][2], 0, 0, 0);
            acc[1][2] = __builtin_amdgcn_mfma_f32_16x16x32_f16(aw1, bh2, acc[1][2], 0, 0, 0);
            acc[2][2] = __builtin_amdgcn_mfma_f32_16x16x32_f16(aw2, bh2, acc[2][2], 0, 0, 0);
            acc[3][2] = __builtin_amdgcn_mfma_f32_16x16x32_f16(aw3, bh2, acc[3][2], 0, 0, 0);
            acc[0][3] = __builtin_amdgcn_mfma_f32_16x16x32_f16(aw0, bh3, acc[0][3], 0, 0, 0);
            acc[1][3] = __builtin_amdgcn_mfma_f32_16x16x32_f16(aw1, bh3, acc[1][3], 0, 0, 0);
            acc[2][3] = __builtin_amdgcn_mfma_f32_16x16x32_f16(aw2, bh3, acc[2][3], 0, 0, 0);
            acc[3][3] = __builtin_amdgcn_mfma_f32_16x16x32_f16(aw3, bh3, acc[3][3], 0, 0, 0);
            __builtin_amdgcn_s_setprio(0);
            aw0 = an0; aw1 = an1; aw2 = an2; aw3 = an3;
            bh0 = bn0; bh1 = bn1;
        }
        // NO guard barrier: writes target the other buffer.
        if (layer < 2) {
#pragma unroll
            for (int mi = 0; mi < 4; ++mi) {
                int c0 = cg * 64 + mi * 16 + quad * 4;
#pragma unroll
                for (int nt = 0; nt < 4; ++nt) {
                    int row = nt * 16 + l15;
                    h16x4 hv;
#pragma unroll
                    for (int v = 0; v < 4; ++v)
                        hv[v] = (half_t)relu_f(acc[mi][nt][v] + biasL[layer][c0 + v]);
                    *(h16x4*)&hw[row * 264 + c0] = hv;
                }
            }
            __syncthreads();                               // single publish barrier
        } else {
#pragma unroll
            for (int mi = 0; mi < 4; ++mi) {
                int c0 = cg * 64 + mi * 16 + quad * 4;
#pragma unroll
                for (int v = 0; v < 4; ++v) {
                    float s = 0.f;
#pragma unroll
                    for (int nt = 0; nt < 4; ++nt) {
                        int row = nt * 16 + l15;
                        float x = relu_f(acc[mi][nt][v] + biasL[2][c0 + v]);
                        if (row < rmax) s += x;
                    }
                    s += __shfl_xor(s, 1);
                    s += __shfl_xor(s, 2);
                    s += __shfl_xor(s, 4);
                    s += __shfl_xor(s, 8);
                    if (l15 == 0) atomicAdd(&xg[b * 256 + c0 + v], s);
                }
            }
        }
    }
}

// ---------------- f-MLP + log_softmax (2 batches per block) ----------------
__global__ __launch_bounds__(256) void k_f(const float* xg, const float* fw1, const float* fb1,
                                           const float* fw2, const float* fb2,
                                           const float* fw3, const float* fb3, float* out) {
    int b0 = blockIdx.x * 2, tid = threadIdx.x;
    __shared__ float xb[2][256], h1[2][256], l10[2][10], red[2];
    xb[0][tid] = xg[b0 * 256 + tid];
    xb[1][tid] = xg[(b0 + 1) * 256 + tid];
    __syncthreads();
    float s0 = fb1[tid], s1 = s0;
    {
        const float4* wr = (const float4*)&fw1[tid * 256];
        const float4* x0 = (const float4*)xb[0];
        const float4* x1 = (const float4*)xb[1];
#pragma unroll 8
        for (int k = 0; k < 64; ++k) {
            float4 w = wr[k], a = x0[k], c = x1[k];
            s0 += w.x * a.x + w.y * a.y + w.z * a.z + w.w * a.w;
            s1 += w.x * c.x + w.y * c.y + w.z * c.z + w.w * c.w;
        }
    }
    h1[0][tid] = relu_f(s0);
    h1[1][tid] = relu_f(s1);
    __syncthreads();
    s0 = fb2[tid]; s1 = s0;
    {
        const float4* wr = (const float4*)&fw2[tid * 256];
        const float4* x0 = (const float4*)h1[0];
        const float4* x1 = (const float4*)h1[1];
#pragma unroll 8
        for (int k = 0; k < 64; ++k) {
            float4 w = wr[k], a = x0[k], c = x1[k];
            s0 += w.x * a.x + w.y * a.y + w.z * a.z + w.w * a.w;
            s1 += w.x * c.x + w.y * c.y + w.z * c.z + w.w * c.w;
        }
    }
    __syncthreads();
    xb[0][tid] = relu_f(s0);
    xb[1][tid] = relu_f(s1);
    __syncthreads();
    if (tid < 20) {
        int bb = tid / 10, o = tid % 10;
        float v = fb3[o];
        const float4* wr = (const float4*)&fw3[o * 256];
        const float4* hv = (const float4*)xb[bb];
#pragma unroll 8
        for (int k = 0; k < 64; ++k) {
            float4 w = wr[k], x = hv[k];
            v += w.x * x.x + w.y * x.y + w.z * x.z + w.w * x.w;
        }
        l10[bb][o] = v;
    }
    __syncthreads();
    if (tid < 2) {
        float m = l10[tid][0];
        for (int i = 1; i < 10; ++i) m = fmaxf(m, l10[tid][i]);
        float e = 0.f;
        for (int i = 0; i < 10; ++i) e += expf(l10[tid][i] - m);
        red[tid] = m + logf(e);
    }
    __syncthreads();
    if (tid < 20) {
        int bb = tid / 10, o = tid % 10;
        out[(b0 + bb) * 10 + o] = l10[bb][o] - red[bb];
    }
}

extern "C" void kernel_launch(void* const* d_in, const int* in_sizes, int n_in,
                              void* d_out, int out_size, void* d_ws, size_t ws_size,
                              hipStream_t stream) {
    const float* img = (const float*)d_in[0];
    const float* qst = (const float*)d_in[1];
    const float* cw[4] = {(const float*)d_in[2], (const float*)d_in[6],
                          (const float*)d_in[10], (const float*)d_in[14]};
    const float* cb[4] = {(const float*)d_in[3], (const float*)d_in[7],
                          (const float*)d_in[11], (const float*)d_in[15]};
    const float* bg[4] = {(const float*)d_in[4], (const float*)d_in[8],
                          (const float*)d_in[12], (const float*)d_in[16]};
    const float* bb[4] = {(const float*)d_in[5], (const float*)d_in[9],
                          (const float*)d_in[13], (const float*)d_in[17]};
    const float* gw1 = (const float*)d_in[18];
    const float* gb1 = (const float*)d_in[19];
    const float* gw2 = (const float*)d_in[20];
    const float* gb2 = (const float*)d_in[21];
    const float* gw3 = (const float*)d_in[22];
    const float* gb3 = (const float*)d_in[23];
    const float* gw4 = (const float*)d_in[24];
    const float* gb4 = (const float*)d_in[25];
    const float* fw1 = (const float*)d_in[26];
    const float* fb1 = (const float*)d_in[27];
    const float* fw2 = (const float*)d_in[28];
    const float* fb2 = (const float*)d_in[29];
    const float* fw3 = (const float*)d_in[30];
    const float* fb3 = (const float*)d_in[31];

    float* ws = (float*)d_ws;
    half_t* y1 = (half_t*)(ws + OFF_Y1);   // f16 intermediate, [img][pix][24ch]
    float* y2 = ws + OFF_Y2;
    float* y3 = ws + OFF_Y3;
    float* y4 = ws + OFF_Y4;
    float* st = ws + OFF_ST;            // 4 layers * 16 slots * 48
    half_t* whl = (half_t*)(ws + OFF_WHL);
    half_t* whl2 = (half_t*)(ws + OFF_WHL2);  // conv2 B-frags (free hole after y1-f16)
    float* A = ws + OFF_A;              // aliases y1 (dead after conv2)
    float* Bv = ws + OFF_BV;
    float* xg = ws + OFF_XG;
    float* out = (float*)d_out;

    k_prep<<<768, 256, 0, stream>>>(gw2, gw3, gw4, whl, st);
    k_prep2<<<28, 256, 0, stream>>>(cw[1], whl2);
    k_conv1<<<1444, 256, 0, stream>>>(img, cw[0], cb[0], y1, st + 0 * 768);
    k_conv2<<<512, 512, 0, stream>>>(y1, whl2, cb[1], st + 0 * 768, bg[0], bb[0], y2,
                                     st + 1 * 768);
    k_conv<<<200, 256, 0, stream>>>(y2, cw[2], cb[2], st + 1 * 768, bg[1], bb[1], y3,
                                    st + 2 * 768, 19, 10, 1.f / 184832.f);
    k_conv<<<50, 256, 0, stream>>>(y3, cw[3], cb[3], st + 2 * 768, bg[2], bb[2], y4,
                                   st + 3 * 768, 10, 5, 1.f / 51200.f);
    k_obj<<<512, 256, 0, stream>>>(y4, qst, gw1, gb1, st + 3 * 768, bg[3], bb[3], A, Bv, xg);
    k_g<<<5120, 256, 0, stream>>>(A, Bv, whl, gb2, gb3, gb4, xg);
    k_f<<<256, 256, 0, stream>>>(xg, fw1, fb1, fw2, fb2, fw3, fb3, out);
}

// Round 15
// 510.686 us; speedup vs baseline: 1.0567x; 1.0567x over previous
//
#include <hip/hip_runtime.h>
#include <hip/hip_bf16.h>

#define EPS 1e-5f

typedef _Float16 half_t;
typedef __attribute__((ext_vector_type(8))) _Float16 h16x8;
typedef __attribute__((ext_vector_type(4))) _Float16 h16x4;
typedef __attribute__((ext_vector_type(4))) float f32x4;

__device__ __forceinline__ float relu_f(float x) { return x > 0.f ? x : 0.f; }

// ---------------- workspace layout (float units) ----------------
#define OFF_Y1   0
#define OFF_Y2   17743872
#define OFF_Y3   22179840
#define OFF_Y4   23408640
#define OFF_ST   23715840
#define OFF_WHL  23718912
// aliases inside y1 region (y1 dead after conv2):
#define OFF_A    0
#define OFF_BV   3276800
#define OFF_XG   6553600
// free hole: y1 as f16 uses only floats [0, 8871936) of its legacy region:
#define OFF_WHL2 8871936

// ---------------- prep: zero stats + cast g_w2..4 to f16, swizzled to A-frag lane order ----
__global__ __launch_bounds__(256) void k_prep(const float* w2, const float* w3,
                                              const float* w4, half_t* whl, float* stats) {
    int idx = blockIdx.x * 256 + threadIdx.x;     // grid exact: 768*256 = 3*65536
    if (idx < 3072) stats[idx] = 0.f;
    int l = idx >> 16, e = idx & 65535;
    const float* w = (l == 0) ? w2 : (l == 1) ? w3 : w4;
    float v = w[e];
    int c = e >> 8, k = e & 255;
    int o = ((c >> 4) * 8 + (k >> 5)) * 512 + ((k >> 3) & 3) * 128 + (c & 15) * 8 + (k & 7);
    whl[l * 65536 + o] = (half_t)v;
}

// ---------------- prep2: conv2 weights -> B-frag layout (K=tap*24+ic pad 224, oc pad 32) ---
__global__ __launch_bounds__(256) void k_prep2(const float* w2, half_t* whl2) {
    int idx = blockIdx.x * 256 + threadIdx.x;     // 28*256 = 7168 exact
    int ntile = idx / 3584, r = idx % 3584;
    int ks = r / 512, w = r % 512;
    int quad = w / 128, l15 = (w >> 3) & 15, j = w & 7;
    int k = ks * 32 + quad * 8 + j;
    int oc = ntile * 16 + l15;
    float v = 0.f;
    if (k < 216 && oc < 24) {
        int tap = k / 24, ic = k % 24;
        v = w2[(oc * 24 + ic) * 9 + tap];
    }
    whl2[idx] = (half_t)v;
}

// ---------------- conv1: 3->24 ch, 75->38, stride2 pad1, 2 images/thread ------------------
__global__ __launch_bounds__(256, 2) void k_conv1(const float* img, const float* w,
                                                  const float* bias, half_t* y1, float* ostats) {
    __shared__ float wl[648], bl[24], red[4][48];
    int tid = threadIdx.x;
    if (tid < 24) bl[tid] = bias[tid];
    for (int i = tid; i < 648; i += 256) wl[i] = w[i];
    __syncthreads();
    int idx = blockIdx.x * 256 + tid;      // 1444*256 = 256*1444 exact (image-pairs)
    int b2 = idx / 1444, rem = idx % 1444;
    int b0 = b2 * 2;
    int oh = rem / 38, ow = rem % 38;
    float acc0[24], acc1[24];
#pragma unroll
    for (int o = 0; o < 24; ++o) { acc0[o] = bl[o]; acc1[o] = bl[o]; }
    for (int ic = 0; ic < 3; ++ic) {
        float p0[9], p1[9];
#pragma unroll
        for (int kh = 0; kh < 3; ++kh) {
            int ih = oh * 2 - 1 + kh;
#pragma unroll
            for (int kw = 0; kw < 3; ++kw) {
                int iw = ow * 2 - 1 + kw;
                bool ok = (unsigned)ih < 75u && (unsigned)iw < 75u;
                p0[kh * 3 + kw] = ok ? img[((b0 * 3 + ic) * 75 + ih) * 75 + iw] : 0.f;
                p1[kh * 3 + kw] = ok ? img[(((b0 + 1) * 3 + ic) * 75 + ih) * 75 + iw] : 0.f;
            }
        }
#pragma unroll
        for (int o = 0; o < 24; ++o)
#pragma unroll
            for (int t = 0; t < 9; ++t) {
                float wv = wl[(o * 3 + ic) * 9 + t];
                acc0[o] += wv * p0[t];
                acc1[o] += wv * p1[t];
            }
    }
#pragma unroll
    for (int o = 0; o < 24; ++o) { acc0[o] = relu_f(acc0[o]); acc1[o] = relu_f(acc1[o]); }
#pragma unroll
    for (int g = 0; g < 3; ++g) {
        h16x8 a, c;
#pragma unroll
        for (int j = 0; j < 8; ++j) { a[j] = (half_t)acc0[g * 8 + j]; c[j] = (half_t)acc1[g * 8 + j]; }
        *(h16x8*)&y1[((long)(b0) * 1444 + rem) * 24 + g * 8] = a;
        *(h16x8*)&y1[((long)(b0 + 1) * 1444 + rem) * 24 + g * 8] = c;
    }
    int wave = tid >> 6;
#pragma unroll
    for (int o = 0; o < 24; ++o) {
        float v = acc0[o] + acc1[o];
        float v2 = acc0[o] * acc0[o] + acc1[o] * acc1[o];
#pragma unroll
        for (int off = 1; off < 64; off <<= 1) { v += __shfl_xor(v, off); v2 += __shfl_xor(v2, off); }
        if ((tid & 63) == 0) { red[wave][o] = v; red[wave][24 + o] = v2; }
    }
    __syncthreads();
    if (tid < 48)
        atomicAdd(&ostats[(blockIdx.x & 15) * 48 + tid],
                  red[0][tid] + red[1][tid] + red[2][tid] + red[3][tid]);
}

// ---------------- conv2 v5: MFMA im2col, 512 threads (R12: kept, -3.5us matched) -----------
__global__ __launch_bounds__(512) void k_conv2(const half_t* yin, const half_t* whl2,
                                               const float* bias, const float* instats,
                                               const float* bng, const float* bnb,
                                               float* yout, float* ostats) {
    __shared__ half_t yL[34672];          // 38*38*24 + zero slot @34656
    __shared__ half_t wf[7168];
    __shared__ float outL[8856];          // 24 x stride 369
    __shared__ float scs[24], shs[24], bl[24], red[8][48];
    int tid = threadIdx.x;
    int b = blockIdx.x;
    if (tid < 24) {
        float s = 0.f, s2 = 0.f;
#pragma unroll
        for (int k = 0; k < 16; ++k) { s += instats[k * 48 + tid]; s2 += instats[k * 48 + 24 + tid]; }
        float mu = s * (1.f / 739328.f);
        float var = s2 * (1.f / 739328.f) - mu * mu;
        float sca = bng[tid] * rsqrtf(var + EPS);
        scs[tid] = sca; shs[tid] = bnb[tid] - mu * sca;
        bl[tid] = bias[tid];
    }
    if (tid < 16) yL[34656 + tid] = (half_t)0.f;   // zero slot (+pad)
    for (int i = tid; i < 896; i += 512)
        ((h16x8*)wf)[i] = ((const h16x8*)whl2)[i];
    __syncthreads();
    // stage image with input-BN applied (channels per 8-chunk never wrap: 24 = 3*8)
    const half_t* ybase = yin + (long)b * 34656;
    for (int i = tid; i < 4332; i += 512) {
        h16x8 v = *(const h16x8*)&ybase[i * 8];
        int ch0 = (i % 3) * 8;
        h16x8 o;
#pragma unroll
        for (int j = 0; j < 8; ++j)
            o[j] = (half_t)((float)v[j] * scs[ch0 + j] + shs[ch0 + j]);
        *(h16x8*)&yL[i * 8] = o;
    }
    __syncthreads();
    int wv = tid >> 6, lane = tid & 63, quad = lane >> 4, l15 = lane & 15;
    float bb0 = bl[l15];
    float bb1 = (l15 < 8) ? bl[16 + l15] : 0.f;
    float s0 = 0.f, q0 = 0.f, s1 = 0.f, q1 = 0.f;
    int t0 = wv * 3, t1 = t0 + 3; if (t1 > 23) t1 = 23;
#pragma unroll 1
    for (int t = t0; t < t1; ++t) {
        int px0 = t * 16;
        int pxa = px0 + l15; if (pxa > 360) pxa = 360;   // A-row clamp; dead rows masked at D
        int oh = pxa / 19, ow = pxa % 19;
        f32x4 a0 = (f32x4){0.f, 0.f, 0.f, 0.f};
        f32x4 a1 = (f32x4){0.f, 0.f, 0.f, 0.f};
#pragma unroll
        for (int ks = 0; ks < 7; ++ks) {
            int k0 = ks * 32 + quad * 8;
            int tap = k0 / 24, ic0 = k0 - tap * 24;
            int kh = tap / 3, kw = tap - kh * 3;
            int ih = oh * 2 - 1 + kh, iw = ow * 2 - 1 + kw;
            bool val = (tap < 9) && ((unsigned)ih < 38u) && ((unsigned)iw < 38u);
            int aoff = val ? ((ih * 38 + iw) * 24 + ic0) : 34656;
            h16x8 af = *(const h16x8*)&yL[aoff];
            h16x8 w0 = *(const h16x8*)&wf[ks * 512 + quad * 128 + l15 * 8];
            h16x8 w1 = *(const h16x8*)&wf[3584 + ks * 512 + quad * 128 + l15 * 8];
            a0 = __builtin_amdgcn_mfma_f32_16x16x32_f16(af, w0, a0, 0, 0, 0);
            a1 = __builtin_amdgcn_mfma_f32_16x16x32_f16(af, w1, a1, 0, 0, 0);
        }
#pragma unroll
        for (int v = 0; v < 4; ++v) {
            int p = px0 + quad * 4 + v;                  // <= 367 < 369: unconditional LDS ok
            bool pv = p < 361;
            float x0 = relu_f(a0[v] + bb0);
            float x1 = relu_f(a1[v] + bb1);
            outL[l15 * 369 + p] = x0;
            if (l15 < 8) outL[(16 + l15) * 369 + p] = x1;
            if (pv) {
                s0 += x0; q0 += x0 * x0;
                if (l15 < 8) { s1 += x1; q1 += x1 * x1; }
            }
        }
    }
    // stats: reduce over quads (lanes sharing l15)
    s0 += __shfl_xor(s0, 16); s0 += __shfl_xor(s0, 32);
    q0 += __shfl_xor(q0, 16); q0 += __shfl_xor(q0, 32);
    s1 += __shfl_xor(s1, 16); s1 += __shfl_xor(s1, 32);
    q1 += __shfl_xor(q1, 16); q1 += __shfl_xor(q1, 32);
    if (quad == 0) {
        red[wv][l15] = s0; red[wv][24 + l15] = q0;
        if (l15 < 8) { red[wv][16 + l15] = s1; red[wv][40 + l15] = q1; }
    }
    __syncthreads();
    float* yo = yout + (long)b * 8664;
    for (int i = tid; i < 8664; i += 512) {
        int oc = i / 361, p = i - oc * 361;
        yo[i] = outL[oc * 369 + p];                      // y2 linear == (b*24+oc)*361+p
    }
    if (tid < 48) {
        float s = 0.f;
#pragma unroll
        for (int w2 = 0; w2 < 8; ++w2) s += red[w2][tid];
        atomicAdd(&ostats[(blockIdx.x & 15) * 48 + tid], s);
    }
}

// ---------------- conv3/4: 24->24, stride2 pad1; in-BN folded; fused out-stats ------------
__global__ __launch_bounds__(256) void k_conv(const float* yin, const float* w,
                                              const float* bias, const float* instats,
                                              const float* bng, const float* bnb,
                                              float* yout, float* ostats,
                                              int Hin, int Hout, float invN) {
    __shared__ float wl[5184], bl[24], sc[24], sh[24], red[4][48];
    int tid = threadIdx.x;
    if (tid < 24) {
        float s = 0.f, s2 = 0.f;
#pragma unroll
        for (int k = 0; k < 16; ++k) { s += instats[k * 48 + tid]; s2 += instats[k * 48 + 24 + tid]; }
        float mu = s * invN;
        float var = s2 * invN - mu * mu;
        float sca = bng[tid] * rsqrtf(var + EPS);
        sc[tid] = sca; sh[tid] = bnb[tid] - mu * sca;
        bl[tid] = bias[tid];
    }
    for (int i = tid; i < 5184; i += 256) wl[i] = w[i];
    __syncthreads();
    int idx = blockIdx.x * 256 + tid;      // grids exact
    int HWo = Hout * Hout;
    int b = idx / HWo, rem = idx % HWo;
    int oh = rem / Hout, ow = rem % Hout;
    float acc[24];
#pragma unroll
    for (int o = 0; o < 24; ++o) acc[o] = bl[o];
    for (int ic = 0; ic < 24; ++ic) {
        float patch[9];
        float scc = sc[ic], shc = sh[ic];
#pragma unroll
        for (int kh = 0; kh < 3; ++kh) {
            int ih = oh * 2 - 1 + kh;
#pragma unroll
            for (int kw = 0; kw < 3; ++kw) {
                int iw = ow * 2 - 1 + kw;
                bool ok = (unsigned)ih < (unsigned)Hin && (unsigned)iw < (unsigned)Hin;
                patch[kh * 3 + kw] = ok ? yin[((b * 24 + ic) * Hin + ih) * Hin + iw] * scc + shc : 0.f;
            }
        }
#pragma unroll
        for (int o = 0; o < 24; ++o)
#pragma unroll
            for (int t = 0; t < 9; ++t) acc[o] += wl[(o * 24 + ic) * 9 + t] * patch[t];
    }
    int wave = tid >> 6;
#pragma unroll
    for (int o = 0; o < 24; ++o) {
        acc[o] = relu_f(acc[o]);
        yout[(b * 24 + o) * HWo + rem] = acc[o];
        float v = acc[o], v2 = v * v;
#pragma unroll
        for (int off = 1; off < 64; off <<= 1) { v += __shfl_xor(v, off); v2 += __shfl_xor(v2, off); }
        if ((tid & 63) == 0) { red[wave][o] = v; red[wave][24 + o] = v2; }
    }
    __syncthreads();
    if (tid < 48)
        atomicAdd(&ostats[(blockIdx.x & 15) * 48 + tid],
                  red[0][tid] + red[1][tid] + red[2][tid] + red[3][tid]);
}

// ---------------- objects: bn4 + coords once into LDS, project through split g_w1 ----------
__global__ __launch_bounds__(256) void k_obj(const float* y4, const float* qst,
                                             const float* w1, const float* b1,
                                             const float* instats, const float* bng,
                                             const float* bnb, float* A, float* Bv, float* xg) {
    int b = blockIdx.x, tid = threadIdx.x;
    __shared__ float w1l[16128];
    __shared__ float objs[25][28];
    __shared__ float sc[24], sh[24], q[11];
    xg[b * 256 + tid] = 0.f;
    for (int i = tid; i < 16128; i += 256) w1l[i] = w1[i];
    if (tid < 24) {
        float s = 0.f, s2 = 0.f;
#pragma unroll
    for (int k = 0; k < 16; ++k) { s += instats[k * 48 + tid]; s2 += instats[k * 48 + 24 + tid]; }
        float mu = s * (1.f / 12800.f);
        float var = s2 * (1.f / 12800.f) - mu * mu;
        float sca = bng[tid] * rsqrtf(var + EPS);
        sc[tid] = sca; sh[tid] = bnb[tid] - mu * sca;
    }
    if (tid < 11) q[tid] = qst[b * 11 + tid];
    __syncthreads();
    for (int i = tid; i < 600; i += 256) {
        int c = i / 25, p = i % 25;
        objs[p][c] = y4[b * 600 + i] * sc[c] + sh[c];
    }
    if (tid < 25) { objs[tid][24] = ((tid / 5) - 2) * 0.5f; objs[tid][25] = ((tid % 5) - 2) * 0.5f; }
    __syncthreads();
    float wr[63];
#pragma unroll
    for (int k = 0; k < 63; ++k) wr[k] = w1l[tid * 63 + k];
    float qdot = b1[tid];
#pragma unroll
    for (int j = 0; j < 11; ++j) qdot += wr[52 + j] * q[j];
#pragma unroll 1
    for (int p = 0; p < 25; ++p) {
        float a = 0.f, bv = qdot;
#pragma unroll
        for (int k = 0; k < 26; ++k) { a += wr[k] * objs[p][k]; bv += wr[26 + k] * objs[p][k]; }
        A[(b * 25 + p) * 256 + tid] = a;
        Bv[(b * 25 + p) * 256 + tid] = bv;
    }
}

// ---------------- fused g-MLP (FINAL: R12 config) ------------------------------------------
// R13 verdict: dbuf/1-barrier at 2 blocks/CU = 199us (fail signal hit) -> TLP (4 blocks/CU)
// is load-bearing, not barrier count. 7 structural variants measured; this 2-barrier,
// 4-block, 64-row config is the empirical optimum (147-151us). k_g closed.
// R14: bench was an infra failure (container acquire, same as R1); resubmitted unchanged.
__global__ __launch_bounds__(256, 4) void k_g(const float* A, const float* Bv, const half_t* whl,
                                              const float* gb2, const float* gb3,
                                              const float* gb4, float* xg) {
    __shared__ alignas(16) half_t h[64 * 264];
    __shared__ float biasL[3][256];
    int tid = threadIdx.x;
    int lb = (blockIdx.x & 7) * 640 + (blockIdx.x >> 3);   // XCD-contiguous (5120%8==0)
    int b = lb / 10, t = lb % 10;
    int r0 = t * 64;
    int rmax = 625 - r0; if (rmax > 64) rmax = 64;
    biasL[0][tid] = gb2[tid];
    biasL[1][tid] = gb3[tid];
    biasL[2][tid] = gb4[tid];
    const float* Ab = A + b * 6400;
    const float* Bb = Bv + b * 6400;
#pragma unroll
    for (int it = 0; it < 16; ++it) {
        int r = it * 4 + (tid >> 6);                       // wave-uniform row
        int rs = __builtin_amdgcn_readfirstlane(r);
        int pr = r0 + rs; if (pr > 624) pr = 624;          // clamp; masked at final sum
        int i = pr % 25, j = pr / 25;                      // scalar div/mod
        int c4 = (tid & 63) << 2;
        float4 av = *(const float4*)&Ab[i * 256 + c4];
        float4 bv = *(const float4*)&Bb[j * 256 + c4];
        h16x4 hv = {(half_t)relu_f(av.x + bv.x), (half_t)relu_f(av.y + bv.y),
                    (half_t)relu_f(av.z + bv.z), (half_t)relu_f(av.w + bv.w)};
        *(h16x4*)&h[r * 264 + c4] = hv;
    }
    __syncthreads();
    int cg = tid >> 6, lane = tid & 63;                    // 4 waves = 4 channel-groups
    int quad = lane >> 4, l15 = lane & 15;
    const half_t* hr = h + l15 * 264;                      // this lane's row base
    const half_t* Wl = whl + (cg * 4) * 8 * 512 + lane * 8;  // wave's W base (mi=0, ks=0)
#pragma unroll 1
    for (int layer = 0; layer < 3; ++layer) {
        const half_t* W = Wl + layer * 65536;
        f32x4 acc[4][4];
#pragma unroll
        for (int mi = 0; mi < 4; ++mi)
#pragma unroll
            for (int nt = 0; nt < 4; ++nt) acc[mi][nt] = (f32x4){0.f, 0.f, 0.f, 0.f};
        // prologue: ks=0 operands in flight
        h16x8 aw0 = *(const h16x8*)&W[0 * 4096];
        h16x8 aw1 = *(const h16x8*)&W[1 * 4096];
        h16x8 aw2 = *(const h16x8*)&W[2 * 4096];
        h16x8 aw3 = *(const h16x8*)&W[3 * 4096];
        h16x8 bh0 = *(const h16x8*)&hr[0 * 4224 + quad * 8];
        h16x8 bh1 = *(const h16x8*)&hr[1 * 4224 + quad * 8];
#pragma unroll 2
        for (int ks = 0; ks < 8; ++ks) {
            int ko = ks * 32 + quad * 8;
            int ksn = (ks + 1) & 7;                 // wrap: harmless redundant load at ks=7
            int kon = ksn * 32 + quad * 8;
            // this-iter second half (covered by nt=0,1 MFMA burst):
            h16x8 bh2 = *(const h16x8*)&hr[2 * 4224 + ko];
            h16x8 bh3 = *(const h16x8*)&hr[3 * 4224 + ko];
            // next-iter W (covered by full 16-MFMA burst):
            h16x8 an0 = *(const h16x8*)&W[0 * 4096 + ksn * 512];
            h16x8 an1 = *(const h16x8*)&W[1 * 4096 + ksn * 512];
            h16x8 an2 = *(const h16x8*)&W[2 * 4096 + ksn * 512];
            h16x8 an3 = *(const h16x8*)&W[3 * 4096 + ksn * 512];
            __builtin_amdgcn_s_setprio(1);
            acc[0][0] = __builtin_amdgcn_mfma_f32_16x16x32_f16(aw0, bh0, acc[0][0], 0, 0, 0);
            acc[1][0] = __builtin_amdgcn_mfma_f32_16x16x32_f16(aw1, bh0, acc[1][0], 0, 0, 0);
            acc[2][0] = __builtin_amdgcn_mfma_f32_16x16x32_f16(aw2, bh0, acc[2][0], 0, 0, 0);
            acc[3][0] = __builtin_amdgcn_mfma_f32_16x16x32_f16(aw3, bh0, acc[3][0], 0, 0, 0);
            acc[0][1] = __builtin_amdgcn_mfma_f32_16x16x32_f16(aw0, bh1, acc[0][1], 0, 0, 0);
            acc[1][1] = __builtin_amdgcn_mfma_f32_16x16x32_f16(aw1, bh1, acc[1][1], 0, 0, 0);
            acc[2][1] = __builtin_amdgcn_mfma_f32_16x16x32_f16(aw2, bh1, acc[2][1], 0, 0, 0);
            acc[3][1] = __builtin_amdgcn_mfma_f32_16x16x32_f16(aw3, bh1, acc[3][1], 0, 0, 0);
            // next-iter first half (covered by nt=2,3 MFMA burst):
            h16x8 bn0 = *(const h16x8*)&hr[0 * 4224 + kon];
            h16x8 bn1 = *(const h16x8*)&hr[1 * 4224 + kon];
            acc[0][2] = __builtin_amdgcn_mfma_f32_16x16x32_f16(aw0, bh2, acc[0][2], 0, 0, 0);
            acc[1][2] = __builtin_amdgcn_mfma_f32_16x16x32_f16(aw1, bh2, acc[1][2], 0, 0, 0);
            acc[2][2] = __builtin_amdgcn_mfma_f32_16x16x32_f16(aw2, bh2, acc[2][2], 0, 0, 0);
            acc[3][2] = __builtin_amdgcn_mfma_f32_16x16x32_f16(aw3, bh2, acc[3][2], 0, 0, 0);
            acc[0][3] = __builtin_amdgcn_mfma_f32_16x16x32_f16(aw0, bh3, acc[0][3], 0, 0, 0);
            acc[1][3] = __builtin_amdgcn_mfma_f32_16x16x32_f16(aw1, bh3, acc[1][3], 0, 0, 0);
            acc[2][3] = __builtin_amdgcn_mfma_f32_16x16x32_f16(aw2, bh3, acc[2][3], 0, 0, 0);
            acc[3][3] = __builtin_amdgcn_mfma_f32_16x16x32_f16(aw3, bh3, acc[3][3], 0, 0, 0);
            __builtin_amdgcn_s_setprio(0);
            aw0 = an0; aw1 = an1; aw2 = an2; aw3 = an3;
            bh0 = bn0; bh1 = bn1;
        }
        __syncthreads();   // all reads of h done; safe to overwrite
        if (layer < 2) {
#pragma unroll
            for (int mi = 0; mi < 4; ++mi) {
                int c0 = cg * 64 + mi * 16 + quad * 4;
#pragma unroll
                for (int nt = 0; nt < 4; ++nt) {
                    int row = nt * 16 + l15;
                    h16x4 hv;
#pragma unroll
                    for (int v = 0; v < 4; ++v)
                        hv[v] = (half_t)relu_f(acc[mi][nt][v] + biasL[layer][c0 + v]);
                    *(h16x4*)&h[row * 264 + c0] = hv;
                }
            }
            __syncthreads();
        } else {
#pragma unroll
            for (int mi = 0; mi < 4; ++mi) {
                int c0 = cg * 64 + mi * 16 + quad * 4;
#pragma unroll
                for (int v = 0; v < 4; ++v) {
                    float s = 0.f;
#pragma unroll
                    for (int nt = 0; nt < 4; ++nt) {
                        int row = nt * 16 + l15;
                        float x = relu_f(acc[mi][nt][v] + biasL[2][c0 + v]);
                        if (row < rmax) s += x;
                    }
                    s += __shfl_xor(s, 1);
                    s += __shfl_xor(s, 2);
                    s += __shfl_xor(s, 4);
                    s += __shfl_xor(s, 8);
                    if (l15 == 0) atomicAdd(&xg[b * 256 + c0 + v], s);
                }
            }
        }
    }
}

// ---------------- f-MLP + log_softmax (2 batches per block) ----------------
__global__ __launch_bounds__(256) void k_f(const float* xg, const float* fw1, const float* fb1,
                                           const float* fw2, const float* fb2,
                                           const float* fw3, const float* fb3, float* out) {
    int b0 = blockIdx.x * 2, tid = threadIdx.x;
    __shared__ float xb[2][256], h1[2][256], l10[2][10], red[2];
    xb[0][tid] = xg[b0 * 256 + tid];
    xb[1][tid] = xg[(b0 + 1) * 256 + tid];
    __syncthreads();
    float s0 = fb1[tid], s1 = s0;
    {
        const float4* wr = (const float4*)&fw1[tid * 256];
        const float4* x0 = (const float4*)xb[0];
        const float4* x1 = (const float4*)xb[1];
#pragma unroll 8
        for (int k = 0; k < 64; ++k) {
            float4 w = wr[k], a = x0[k], c = x1[k];
            s0 += w.x * a.x + w.y * a.y + w.z * a.z + w.w * a.w;
            s1 += w.x * c.x + w.y * c.y + w.z * c.z + w.w * c.w;
        }
    }
    h1[0][tid] = relu_f(s0);
    h1[1][tid] = relu_f(s1);
    __syncthreads();
    s0 = fb2[tid]; s1 = s0;
    {
        const float4* wr = (const float4*)&fw2[tid * 256];
        const float4* x0 = (const float4*)h1[0];
        const float4* x1 = (const float4*)h1[1];
#pragma unroll 8
        for (int k = 0; k < 64; ++k) {
            float4 w = wr[k], a = x0[k], c = x1[k];
            s0 += w.x * a.x + w.y * a.y + w.z * a.z + w.w * a.w;
            s1 += w.x * c.x + w.y * c.y + w.z * c.z + w.w * c.w;
        }
    }
    __syncthreads();
    xb[0][tid] = relu_f(s0);
    xb[1][tid] = relu_f(s1);
    __syncthreads();
    if (tid < 20) {
        int bb = tid / 10, o = tid % 10;
        float v = fb3[o];
        const float4* wr = (const float4*)&fw3[o * 256];
        const float4* hv = (const float4*)xb[bb];
#pragma unroll 8
        for (int k = 0; k < 64; ++k) {
            float4 w = wr[k], x = hv[k];
            v += w.x * x.x + w.y * x.y + w.z * x.z + w.w * x.w;
        }
        l10[bb][o] = v;
    }
    __syncthreads();
    if (tid < 2) {
        float m = l10[tid][0];
        for (int i = 1; i < 10; ++i) m = fmaxf(m, l10[tid][i]);
        float e = 0.f;
        for (int i = 0; i < 10; ++i) e += expf(l10[tid][i] - m);
        red[tid] = m + logf(e);
    }
    __syncthreads();
    if (tid < 20) {
        int bb = tid / 10, o = tid % 10;
        out[(b0 + bb) * 10 + o] = l10[bb][o] - red[bb];
    }
}

extern "C" void kernel_launch(void* const* d_in, const int* in_sizes, int n_in,
                              void* d_out, int out_size, void* d_ws, size_t ws_size,
                              hipStream_t stream) {
    const float* img = (const float*)d_in[0];
    const float* qst = (const float*)d_in[1];
    const float* cw[4] = {(const float*)d_in[2], (const float*)d_in[6],
                          (const float*)d_in[10], (const float*)d_in[14]};
    const float* cb[4] = {(const float*)d_in[3], (const float*)d_in[7],
                          (const float*)d_in[11], (const float*)d_in[15]};
    const float* bg[4] = {(const float*)d_in[4], (const float*)d_in[8],
                          (const float*)d_in[12], (const float*)d_in[16]};
    const float* bb[4] = {(const float*)d_in[5], (const float*)d_in[9],
                          (const float*)d_in[13], (const float*)d_in[17]};
    const float* gw1 = (const float*)d_in[18];
    const float* gb1 = (const float*)d_in[19];
    const float* gw2 = (const float*)d_in[20];
    const float* gb2 = (const float*)d_in[21];
    const float* gw3 = (const float*)d_in[22];
    const float* gb3 = (const float*)d_in[23];
    const float* gw4 = (const float*)d_in[24];
    const float* gb4 = (const float*)d_in[25];
    const float* fw1 = (const float*)d_in[26];
    const float* fb1 = (const float*)d_in[27];
    const float* fw2 = (const float*)d_in[28];
    const float* fb2 = (const float*)d_in[29];
    const float* fw3 = (const float*)d_in[30];
    const float* fb3 = (const float*)d_in[31];

    float* ws = (float*)d_ws;
    half_t* y1 = (half_t*)(ws + OFF_Y1);   // f16 intermediate, [img][pix][24ch]
    float* y2 = ws + OFF_Y2;
    float* y3 = ws + OFF_Y3;
    float* y4 = ws + OFF_Y4;
    float* st = ws + OFF_ST;            // 4 layers * 16 slots * 48
    half_t* whl = (half_t*)(ws + OFF_WHL);
    half_t* whl2 = (half_t*)(ws + OFF_WHL2);  // conv2 B-frags (free hole after y1-f16)
    float* A = ws + OFF_A;              // aliases y1 (dead after conv2)
    float* Bv = ws + OFF_BV;
    float* xg = ws + OFF_XG;
    float* out = (float*)d_out;

    k_prep<<<768, 256, 0, stream>>>(gw2, gw3, gw4, whl, st);
    k_prep2<<<28, 256, 0, stream>>>(cw[1], whl2);
    k_conv1<<<1444, 256, 0, stream>>>(img, cw[0], cb[0], y1, st + 0 * 768);
    k_conv2<<<512, 512, 0, stream>>>(y1, whl2, cb[1], st + 0 * 768, bg[0], bb[0], y2,
                                     st + 1 * 768);
    k_conv<<<200, 256, 0, stream>>>(y2, cw[2], cb[2], st + 1 * 768, bg[1], bb[1], y3,
                                    st + 2 * 768, 19, 10, 1.f / 184832.f);
    k_conv<<<50, 256, 0, stream>>>(y3, cw[3], cb[3], st + 2 * 768, bg[2], bb[2], y4,
                                   st + 3 * 768, 10, 5, 1.f / 51200.f);
    k_obj<<<512, 256, 0, stream>>>(y4, qst, gw1, gb1, st + 3 * 768, bg[3], bb[3], A, Bv, xg);
    k_g<<<5120, 256, 0, stream>>>(A, Bv, whl, gb2, gb3, gb4, xg);
    k_f<<<256, 256, 0, stream>>>(xg, fw1, fb1, fw2, fb2, fw3, fb3, out);
}